// Round 5
// baseline (2394.901 us; speedup 1.0000x reference)
//
#include <hip/hip_runtime.h>
#include <hip/hip_bf16.h>
#include <stdint.h>

typedef __bf16 bf16_t;
typedef bf16_t bf16x8 __attribute__((ext_vector_type(8)));
typedef float  f32x4  __attribute__((ext_vector_type(4)));

// ---------------- embed: h[i] = x_emb1[x[i,0]] + x_emb2[x[i,1]] ----------------
__global__ void embed_kernel(const int* __restrict__ x, const float* __restrict__ e1,
                             const float* __restrict__ e2, bf16_t* __restrict__ h, int N) {
  const int w = (blockIdx.x * blockDim.x + threadIdx.x) >> 6;
  const int lane = threadIdx.x & 63;
  if (w >= N || lane >= 40) return;
  const int t0 = x[2 * w], t1 = x[2 * w + 1];
  const int co = lane * 8;
  f32x4 a0 = *(const f32x4*)&e1[t0 * 300 + co];
  f32x4 a1 = *(const f32x4*)&e1[t0 * 300 + co + 4];
  f32x4 b0 = *(const f32x4*)&e2[t1 * 300 + co];
  f32x4 b1 = *(const f32x4*)&e2[t1 * 300 + co + 4];
  bf16x8 o;
  #pragma unroll
  for (int j = 0; j < 8; j++) {
    float v = (j < 4) ? (a0[j] + b0[j]) : (a1[j - 4] + b1[j - 4]);
    o[j] = (co + j < 300) ? (bf16_t)v : (bf16_t)0.f;
  }
  *(bf16x8*)&h[(size_t)w * 320 + co] = o;
}

// ---------------- CSR build ----------------
__global__ void count_deg_kernel(const int* __restrict__ ei, int* __restrict__ deg, int E) {
  int e = blockIdx.x * 256 + threadIdx.x;
  if (e < E) atomicAdd(&deg[ei[E + e]], 1);
}

__global__ void scan_partial_kernel(const int* __restrict__ deg, int* __restrict__ part, int N) {
  __shared__ int s[256];
  const int tid = threadIdx.x;
  const int idx = blockIdx.x * 256 + tid;
  s[tid] = (idx < N) ? deg[idx] : 0;
  __syncthreads();
  for (int off = 128; off > 0; off >>= 1) {
    if (tid < off) s[tid] += s[tid + off];
    __syncthreads();
  }
  if (tid == 0) part[blockIdx.x] = s[0];
}

__global__ void scan_block_kernel(int* __restrict__ part, int n) {  // n <= 1024
  __shared__ int s[1024];
  const int tid = threadIdx.x;
  const int v = (tid < n) ? part[tid] : 0;
  s[tid] = v;
  __syncthreads();
  for (int off = 1; off < 1024; off <<= 1) {
    int x = (tid >= off) ? s[tid - off] : 0;
    __syncthreads();
    s[tid] += x;
    __syncthreads();
  }
  if (tid < n) part[tid] = s[tid] - v;  // exclusive
}

__global__ void scan_final_kernel(const int* __restrict__ deg, const int* __restrict__ part,
                                  int* __restrict__ rowptr, int* __restrict__ cursor, int N, int E) {
  __shared__ int s[256];
  const int tid = threadIdx.x;
  const int idx = blockIdx.x * 256 + tid;
  const int v = (idx < N) ? deg[idx] : 0;
  s[tid] = v;
  __syncthreads();
  for (int off = 1; off < 256; off <<= 1) {
    int x = (tid >= off) ? s[tid - off] : 0;
    __syncthreads();
    s[tid] += x;
    __syncthreads();
  }
  if (idx < N) {
    int ex = s[tid] - v + part[blockIdx.x];
    rowptr[idx] = ex;
    cursor[idx] = ex;
  }
  if (idx == 0) rowptr[N] = E;
}

// pack src | (a0*3+a1)<<20
__global__ void fill_csr_kernel(const int* __restrict__ ei, const int* __restrict__ ea,
                                int* __restrict__ cursor, int* __restrict__ epack, int E) {
  int e = blockIdx.x * 256 + threadIdx.x;
  if (e >= E) return;
  int slot = atomicAdd(&cursor[ei[E + e]], 1);
  int a = ea[2 * e] * 3 + ea[2 * e + 1];
  epack[slot] = (ei[e] & 0xFFFFF) | (a << 20);
}

// ---------------- weight convert+transpose+pad to bf16 ----------------
__global__ void convert_w1_kernel(const float* __restrict__ w1, bf16_t* __restrict__ o) {
  int id = blockIdx.x * 256 + threadIdx.x;
  if (id >= 5 * 640 * 320) return;
  int k = id % 320;
  int n = (id / 320) % 640;
  int l = id / (320 * 640);
  float v = (k < 300 && n < 600) ? w1[(size_t)l * 300 * 600 + (size_t)k * 600 + n] : 0.f;
  o[id] = (bf16_t)v;
}

__global__ void convert_w2_kernel(const float* __restrict__ w2, bf16_t* __restrict__ o) {
  int id = blockIdx.x * 256 + threadIdx.x;
  if (id >= 5 * 384 * 640) return;
  int k = id % 640;
  int n = (id / 640) % 384;
  int l = id / (640 * 384);
  float v = (k < 600 && n < 300) ? w2[(size_t)l * 600 * 300 + (size_t)k * 300 + n] : 0.f;
  o[id] = (bf16_t)v;
}

// combined edge table: T12[l][a0*3+a1][col] = ee1[l][a0][col] + ee2[l][a1][col]
__global__ void build_t12_kernel(const float* __restrict__ ee1, const float* __restrict__ ee2,
                                 bf16_t* __restrict__ T12) {
  int id = blockIdx.x * 256 + threadIdx.x;
  if (id >= 5 * 21 * 320) return;
  int col = id % 320;
  int r = id / 320;
  int l = r / 21;
  int a = r % 21;
  int a0 = a / 3, a1 = a % 3;
  float v = 0.f;
  if (col < 300) v = ee1[((size_t)l * 7 + a0) * 300 + col] + ee2[((size_t)l * 3 + a1) * 300 + col];
  T12[id] = (bf16_t)v;
}

// ---------------- aggregation: thread-centric (node = g/40), fused BN ----------
template <bool FUSE_BN>
__global__ void aggregate_kernel(const bf16_t* __restrict__ hsrc, const int* __restrict__ rowptr,
                                 const int* __restrict__ epack, const bf16_t* __restrict__ T12L,
                                 const float* __restrict__ scale, const float* __restrict__ shift,
                                 bf16_t* __restrict__ agg, int N, int LDH) {
  const int g = blockIdx.x * 256 + threadIdx.x;
  const int w = g / 40;
  if (w >= N) return;
  const int co = (g - w * 40) * 8;

  float sc[8], sh[8];
  if (FUSE_BN) {
    f32x4 s0 = *(const f32x4*)&scale[co];
    f32x4 s1 = *(const f32x4*)&scale[co + 4];
    f32x4 t0 = *(const f32x4*)&shift[co];
    f32x4 t1 = *(const f32x4*)&shift[co + 4];
    #pragma unroll
    for (int j = 0; j < 4; j++) { sc[j] = s0[j]; sc[j + 4] = s1[j]; sh[j] = t0[j]; sh[j + 4] = t1[j]; }
  }

  const int beg = rowptr[w], end = rowptr[w + 1];
  float acc[8];
  {
    bf16x8 hv = *(const bf16x8*)&hsrc[(size_t)w * LDH + co];
    bf16x8 tv = *(const bf16x8*)&T12L[12 * 320 + co];  // self loop: a0=4,a1=0
    #pragma unroll
    for (int j = 0; j < 8; j++) {
      float v = (float)hv[j];
      if (FUSE_BN) v = fmaxf(v * sc[j] + sh[j], 0.f);
      acc[j] = v + (float)tv[j];
    }
  }
  for (int e = beg; e < end; e++) {
    const int p = epack[e];
    const int s = p & 0xFFFFF;
    const int a = (p >> 20) & 0x1F;
    bf16x8 hv = *(const bf16x8*)&hsrc[(size_t)s * LDH + co];
    bf16x8 tv = *(const bf16x8*)&T12L[a * 320 + co];
    #pragma unroll
    for (int j = 0; j < 8; j++) {
      float v = (float)hv[j];
      if (FUSE_BN) v = fmaxf(v * sc[j] + sh[j], 0.f);
      acc[j] += v + (float)tv[j];
    }
  }
  bf16x8 o;
  #pragma unroll
  for (int j = 0; j < 8; j++) o[j] = (bf16_t)acc[j];
  *(bf16x8*)&agg[(size_t)w * 320 + co] = o;
}

// ---------------- MFMA GEMM: NO-LDS, register-fragment, barrier-free -----------
// Rounds 0-4: four different LDS schedules all pinned at 17-18% MfmaUtil -- the
// barrier+LDS lockstep itself is the stall. Here each wave loads its own MFMA
// fragments DIRECTLY global->VGPR: lane(ml,quad) reads 16B at row(ml), k-chunk
// (quad) -- 64 lanes cover exactly 16 cache lines per load (perfect coalescing).
// B panels are XCD-L2-resident (y-fastest + XCD swizzle keeps all of W1/W2 in
// the 4MB XCD L2); A is L2/L3-hot after first y-tile. No barriers, no ds ops:
// 3 independent waves/SIMD hide the ~200-260cy L2 latency under each wave's
// ~310cy MFMA phase. Depth-1 register double-buffer, fully unrolled (NK is a
// template constant -> all fragment indices static, K-offsets fold into the
// 13-bit global_load immediate).
// Grid: 1-D y-fastest + bijective XCD chunk swizzle. STATS: fused BN col stats.
template <int LDA, int LDB, int LDC, int NK, int GY, int NBIAS, bool RELU, bool STATS>
__global__ __launch_bounds__(256, 3) void gemm_kernel(const bf16_t* __restrict__ A,
                                                      const bf16_t* __restrict__ BT,
                                                      const float* __restrict__ bias,
                                                      bf16_t* __restrict__ C,
                                                      float* __restrict__ sums,
                                                      float* __restrict__ sumsq,
                                                      int Nvalid, int nwg) {
  const int tid = threadIdx.x;
  const int lane = tid & 63;
  const int wave = tid >> 6;
  const int ml = lane & 15, quad = lane >> 4;
  const int wm = (wave & 1) * 64, wn = (wave >> 1) * 64;

  // bijective XCD swizzle
  const int bid = blockIdx.x;
  const int q = nwg >> 3, r = nwg & 7;
  const int xcd = bid & 7, pos = bid >> 3;
  const int logical = (xcd < r ? xcd * (q + 1) : r * (q + 1) + (xcd - r) * q) + pos;
  const size_t bm = (size_t)(logical / GY) * 128;
  const size_t bnn = (size_t)(logical % GY) * 128;

  // per-lane fragment base pointers: row = bm+wm+mf*16+ml, k-chunk = quad*8
  const bf16_t* aB = A + (bm + wm + ml) * LDA + quad * 8;
  const bf16_t* bB = BT + (bnn + wn + ml) * LDB + quad * 8;

  f32x4 acc[4][4];
  #pragma unroll
  for (int rr = 0; rr < 4; rr++)
    #pragma unroll
    for (int cc = 0; cc < 4; cc++) acc[rr][cc] = (f32x4){0.f, 0.f, 0.f, 0.f};

  bf16x8 aR[2][4], bR[2][4];
  #pragma unroll
  for (int mf = 0; mf < 4; mf++) aR[0][mf] = *(const bf16x8*)(aB + (size_t)mf * 16 * LDA);
  #pragma unroll
  for (int nf = 0; nf < 4; nf++) bR[0][nf] = *(const bf16x8*)(bB + (size_t)nf * 16 * LDB);

  #pragma unroll
  for (int kb = 0; kb < NK; kb++) {
    const int cur = kb & 1, nxt = cur ^ 1;
    if (kb + 1 < NK) {
      #pragma unroll
      for (int mf = 0; mf < 4; mf++)
        aR[nxt][mf] = *(const bf16x8*)(aB + (size_t)mf * 16 * LDA + (kb + 1) * 32);
      #pragma unroll
      for (int nf = 0; nf < 4; nf++)
        bR[nxt][nf] = *(const bf16x8*)(bB + (size_t)nf * 16 * LDB + (kb + 1) * 32);
    }
    #pragma unroll
    for (int mf = 0; mf < 4; mf++)
      #pragma unroll
      for (int nf = 0; nf < 4; nf++)
        acc[mf][nf] = __builtin_amdgcn_mfma_f32_16x16x32_bf16(aR[cur][mf], bR[cur][nf],
                                                              acc[mf][nf], 0, 0, 0);
  }

  // epilogue: C/D layout col=lane&15, row=quad*4+reg
  #pragma unroll
  for (int nf = 0; nf < 4; nf++) {
    const int colg = (int)bnn + wn + nf * 16 + ml;
    const float bv = (colg < NBIAS) ? bias[colg] : 0.f;
    float s = 0.f, sq = 0.f;
    #pragma unroll
    for (int mf = 0; mf < 4; mf++) {
      #pragma unroll
      for (int i = 0; i < 4; i++) {
        const size_t rowg = bm + wm + mf * 16 + quad * 4 + i;
        float v = acc[mf][nf][i] + bv;
        if (RELU) v = fmaxf(v, 0.f);
        C[rowg * LDC + colg] = (bf16_t)v;
        if (STATS) {
          const bool ok = rowg < (size_t)Nvalid;
          s += ok ? v : 0.f;
          sq += ok ? v * v : 0.f;
        }
      }
    }
    if (STATS) {
      s += __shfl_down(s, 16);
      sq += __shfl_down(sq, 16);
      s += __shfl_down(s, 32);
      sq += __shfl_down(sq, 32);
      if (quad == 0) {
        atomicAdd(&sums[colg], s);
        atomicAdd(&sumsq[colg], sq);
      }
    }
  }
}

// ---------------- BN ----------------
__global__ void bn_params_kernel(const float* __restrict__ sums, const float* __restrict__ sumsq,
                                 const float* __restrict__ gamma, const float* __restrict__ beta,
                                 float* __restrict__ scale, float* __restrict__ shift, int N) {
  const int col = threadIdx.x;
  if (col >= 384) return;
  if (col >= 300) {  // pad cols: force transformed pad to 0
    scale[col] = 0.f;
    shift[col] = 0.f;
    return;
  }
  const float inv = 1.f / (float)N;
  const float mean = sums[col] * inv;
  float var = sumsq[col] * inv - mean * mean;
  if (var < 0.f) var = 0.f;
  const float sc = gamma[col] * rsqrtf(var + 1e-5f);
  scale[col] = sc;
  shift[col] = beta[col] - mean * sc;
}

// final-layer output: wave per node, lane<40 handles 8 cols, writes f32 out
__global__ void bn_apply_kernel(const bf16_t* __restrict__ H2, const float* __restrict__ scale,
                                const float* __restrict__ shift, float* __restrict__ out, int N) {
  const int w = (blockIdx.x * blockDim.x + threadIdx.x) >> 6;
  const int lane = threadIdx.x & 63;
  if (w >= N || lane >= 40) return;
  const int co = lane * 8;
  bf16x8 v8 = *(const bf16x8*)&H2[(size_t)w * 384 + co];
  f32x4 s0 = *(const f32x4*)&scale[co];
  f32x4 s1 = *(const f32x4*)&scale[co + 4];
  f32x4 t0 = *(const f32x4*)&shift[co];
  f32x4 t1 = *(const f32x4*)&shift[co + 4];
  #pragma unroll
  for (int j = 0; j < 8; j++) {
    float sc = (j < 4) ? s0[j] : s1[j - 4];
    float sh = (j < 4) ? t0[j] : t1[j - 4];
    float v = (float)v8[j] * sc + sh;
    if (co + j < 300) out[(size_t)w * 300 + co + j] = v;
  }
}

// ---------------- launch ----------------
extern "C" void kernel_launch(void* const* d_in, const int* in_sizes, int n_in,
                              void* d_out, int out_size, void* d_ws, size_t ws_size,
                              hipStream_t stream) {
  const int* x = (const int*)d_in[0];
  const int* ei = (const int*)d_in[1];
  const int* ea = (const int*)d_in[2];
  const float* xe1 = (const float*)d_in[3];
  const float* xe2 = (const float*)d_in[4];
  const float* ee1 = (const float*)d_in[5];
  const float* ee2 = (const float*)d_in[6];
  const float* w1 = (const float*)d_in[7];
  const float* b1 = (const float*)d_in[8];
  const float* w2 = (const float*)d_in[9];
  const float* b2 = (const float*)d_in[10];
  const float* gam = (const float*)d_in[11];
  const float* bet = (const float*)d_in[12];

  const int N = in_sizes[0] / 2;   // 100000
  const int E = in_sizes[1] / 2;   // 200000
  const int Mt = (N + 127) / 128;  // 782
  const size_t Mp = (size_t)Mt * 128;

  char* p = (char*)d_ws;
  auto take = [&](size_t b) -> char* {
    char* r = p;
    p += (b + 255) & ~(size_t)255;
    return r;
  };
  bf16_t* h    = (bf16_t*)take(Mp * 320 * 2);
  bf16_t* agg  = (bf16_t*)take(Mp * 320 * 2);
  bf16_t* C1   = (bf16_t*)take(Mp * 640 * 2);
  bf16_t* H2   = (bf16_t*)take(Mp * 384 * 2);
  bf16_t* W1bT = (bf16_t*)take((size_t)5 * 640 * 320 * 2);
  bf16_t* W2bT = (bf16_t*)take((size_t)5 * 384 * 640 * 2);
  bf16_t* T12  = (bf16_t*)take((size_t)5 * 21 * 320 * 2);
  int* deg     = (int*)take((size_t)N * 4);
  int* rowptr  = (int*)take((size_t)(N + 1) * 4);
  int* cursor  = (int*)take((size_t)N * 4);
  int* part    = (int*)take(1024 * 4);
  int* epack   = (int*)take((size_t)E * 4);
  float* sums  = (float*)take(384 * 4);
  float* sumsq = (float*)take(384 * 4);
  float* scale = (float*)take(384 * 4);
  float* shift = (float*)take(384 * 4);

  // agg pad rows must be exact zeros for GEMM1 (aggregate writes rows<N only)
  hipMemsetAsync(agg, 0, Mp * 320 * 2, stream);
  hipMemsetAsync(deg, 0, (size_t)N * 4, stream);

  const int nwb = (N + 3) / 4;  // wave-per-node kernels
  embed_kernel<<<nwb, 256, 0, stream>>>(x, xe1, xe2, h, N);

  count_deg_kernel<<<(E + 255) / 256, 256, 0, stream>>>(ei, deg, E);
  const int nsb = (N + 255) / 256;  // 391 (<=1024 for scan_block)
  scan_partial_kernel<<<nsb, 256, 0, stream>>>(deg, part, N);
  scan_block_kernel<<<1, 1024, 0, stream>>>(part, nsb);
  scan_final_kernel<<<nsb, 256, 0, stream>>>(deg, part, rowptr, cursor, N, E);
  fill_csr_kernel<<<(E + 255) / 256, 256, 0, stream>>>(ei, ea, cursor, epack, E);

  convert_w1_kernel<<<(5 * 640 * 320 + 255) / 256, 256, 0, stream>>>(w1, W1bT);
  convert_w2_kernel<<<(5 * 384 * 640 + 255) / 256, 256, 0, stream>>>(w2, W2bT);
  build_t12_kernel<<<(5 * 21 * 320 + 255) / 256, 256, 0, stream>>>(ee1, ee2, T12);

  const int nwg1 = Mt * 5;  // 3910
  const int nwg2 = Mt * 3;  // 2346
  const int nab = (N * 40 + 255) / 256;  // thread-centric aggregate grid

  for (int l = 0; l < 5; l++) {
    if (l == 0) {
      aggregate_kernel<false><<<nab, 256, 0, stream>>>(h, rowptr, epack,
                                                       T12 + (size_t)l * 21 * 320,
                                                       scale, shift, agg, N, 320);
    } else {
      aggregate_kernel<true><<<nab, 256, 0, stream>>>(H2, rowptr, epack,
                                                      T12 + (size_t)l * 21 * 320,
                                                      scale, shift, agg, N, 384);
    }
    // GEMM1: [Mp,320] x W1T[640,320] -> C1[Mp,640], bias b1 (600), ReLU
    gemm_kernel<320, 320, 640, 10, 5, 600, true, false>
        <<<nwg1, 256, 0, stream>>>(agg, W1bT + (size_t)l * 640 * 320,
                                   b1 + (size_t)l * 600, C1, sums, sumsq, N, nwg1);
    // zero stats before GEMM2's fused bn_stats epilogue
    hipMemsetAsync(sums, 0, 384 * 4, stream);
    hipMemsetAsync(sumsq, 0, 384 * 4, stream);
    // GEMM2: [Mp,640] x W2T[384,640] -> H2[Mp,384], bias b2 (300), fused col stats
    gemm_kernel<640, 640, 384, 20, 3, 300, false, true>
        <<<nwg2, 256, 0, stream>>>(C1, W2bT + (size_t)l * 384 * 640,
                                   b2 + (size_t)l * 300, H2, sums, sumsq, N, nwg2);
    bn_params_kernel<<<1, 384, 0, stream>>>(sums, sumsq, gam + (size_t)l * 300,
                                            bet + (size_t)l * 300, scale, shift, N);
  }
  // final layer output: BN(H2) -> f32 out
  bn_apply_kernel<<<nwb, 256, 0, stream>>>(H2, scale, shift, (float*)d_out, N);
}

// Round 6
// 1384.440 us; speedup vs baseline: 1.7299x; 1.7299x over previous
//
#include <hip/hip_runtime.h>
#include <hip/hip_bf16.h>
#include <stdint.h>

typedef __bf16 bf16_t;
typedef bf16_t bf16x8 __attribute__((ext_vector_type(8)));
typedef bf16_t bf16x4 __attribute__((ext_vector_type(4)));
typedef float  f32x4  __attribute__((ext_vector_type(4)));

// ---------------- embed: h[i] = x_emb1[x[i,0]] + x_emb2[x[i,1]] ----------------
__global__ void embed_kernel(const int* __restrict__ x, const float* __restrict__ e1,
                             const float* __restrict__ e2, bf16_t* __restrict__ h, int N) {
  const int w = (blockIdx.x * blockDim.x + threadIdx.x) >> 6;
  const int lane = threadIdx.x & 63;
  if (w >= N || lane >= 40) return;
  const int t0 = x[2 * w], t1 = x[2 * w + 1];
  const int co = lane * 8;
  f32x4 a0 = *(const f32x4*)&e1[t0 * 300 + co];
  f32x4 a1 = *(const f32x4*)&e1[t0 * 300 + co + 4];
  f32x4 b0 = *(const f32x4*)&e2[t1 * 300 + co];
  f32x4 b1 = *(const f32x4*)&e2[t1 * 300 + co + 4];
  bf16x8 o;
  #pragma unroll
  for (int j = 0; j < 8; j++) {
    float v = (j < 4) ? (a0[j] + b0[j]) : (a1[j - 4] + b1[j - 4]);
    o[j] = (co + j < 300) ? (bf16_t)v : (bf16_t)0.f;
  }
  *(bf16x8*)&h[(size_t)w * 320 + co] = o;
}

// ---------------- CSR build ----------------
__global__ void count_deg_kernel(const int* __restrict__ ei, int* __restrict__ deg, int E) {
  int e = blockIdx.x * 256 + threadIdx.x;
  if (e < E) atomicAdd(&deg[ei[E + e]], 1);
}

__global__ void scan_partial_kernel(const int* __restrict__ deg, int* __restrict__ part, int N) {
  __shared__ int s[256];
  const int tid = threadIdx.x;
  const int idx = blockIdx.x * 256 + tid;
  s[tid] = (idx < N) ? deg[idx] : 0;
  __syncthreads();
  for (int off = 128; off > 0; off >>= 1) {
    if (tid < off) s[tid] += s[tid + off];
    __syncthreads();
  }
  if (tid == 0) part[blockIdx.x] = s[0];
}

__global__ void scan_block_kernel(int* __restrict__ part, int n) {  // n <= 1024
  __shared__ int s[1024];
  const int tid = threadIdx.x;
  const int v = (tid < n) ? part[tid] : 0;
  s[tid] = v;
  __syncthreads();
  for (int off = 1; off < 1024; off <<= 1) {
    int x = (tid >= off) ? s[tid - off] : 0;
    __syncthreads();
    s[tid] += x;
    __syncthreads();
  }
  if (tid < n) part[tid] = s[tid] - v;  // exclusive
}

__global__ void scan_final_kernel(const int* __restrict__ deg, const int* __restrict__ part,
                                  int* __restrict__ rowptr, int* __restrict__ cursor, int N, int E) {
  __shared__ int s[256];
  const int tid = threadIdx.x;
  const int idx = blockIdx.x * 256 + tid;
  const int v = (idx < N) ? deg[idx] : 0;
  s[tid] = v;
  __syncthreads();
  for (int off = 1; off < 256; off <<= 1) {
    int x = (tid >= off) ? s[tid - off] : 0;
    __syncthreads();
    s[tid] += x;
    __syncthreads();
  }
  if (idx < N) {
    int ex = s[tid] - v + part[blockIdx.x];
    rowptr[idx] = ex;
    cursor[idx] = ex;
  }
  if (idx == 0) rowptr[N] = E;
}

// pack src | (a0*3+a1)<<20
__global__ void fill_csr_kernel(const int* __restrict__ ei, const int* __restrict__ ea,
                                int* __restrict__ cursor, int* __restrict__ epack, int E) {
  int e = blockIdx.x * 256 + threadIdx.x;
  if (e >= E) return;
  int slot = atomicAdd(&cursor[ei[E + e]], 1);
  int a = ea[2 * e] * 3 + ea[2 * e + 1];
  epack[slot] = (ei[e] & 0xFFFFF) | (a << 20);
}

// ------------- weight convert: FRAGMENT-MAJOR layout (contiguous 1KB wave loads) --
// W1f[l][nt 40][ks 10][lane 64][8]: lane(ml,quad) elem j = W1T[nt*16+ml][ks*32+quad*8+j]
__global__ void convert_w1_kernel(const float* __restrict__ w1, bf16_t* __restrict__ o) {
  int id = blockIdx.x * 256 + threadIdx.x;
  if (id >= 5 * 40 * 10 * 512) return;
  int j = id & 7;
  int lane = (id >> 3) & 63;
  int rest = id >> 9;
  int ks = rest % 10;
  int nt = (rest / 10) % 40;
  int l = rest / 400;
  int ml = lane & 15, quad = lane >> 4;
  int n = nt * 16 + ml;
  int k = ks * 32 + quad * 8 + j;
  float v = (k < 300 && n < 600) ? w1[((size_t)l * 300 + k) * 600 + n] : 0.f;
  o[id] = (bf16_t)v;
}

// W2f[l][nt 24][ks 20][lane 64][8]: elem = W2T[nt*16+ml][ks*32+quad*8+j]
__global__ void convert_w2_kernel(const float* __restrict__ w2, bf16_t* __restrict__ o) {
  int id = blockIdx.x * 256 + threadIdx.x;
  if (id >= 5 * 24 * 20 * 512) return;
  int j = id & 7;
  int lane = (id >> 3) & 63;
  int rest = id >> 9;
  int ks = rest % 20;
  int nt = (rest / 20) % 24;
  int l = rest / 480;
  int ml = lane & 15, quad = lane >> 4;
  int n = nt * 16 + ml;
  int k = ks * 32 + quad * 8 + j;
  float v = (k < 600 && n < 300) ? w2[((size_t)l * 600 + k) * 300 + n] : 0.f;
  o[id] = (bf16_t)v;
}

// zero-padded biases: b1p[5][640], b2p[5][384]
__global__ void pad_bias_kernel(const float* __restrict__ b1, const float* __restrict__ b2,
                                float* __restrict__ b1p, float* __restrict__ b2p) {
  int t = blockIdx.x * 256 + threadIdx.x;
  if (t < 5 * 640) {
    int l = t / 640, n = t % 640;
    b1p[t] = (n < 600) ? b1[l * 600 + n] : 0.f;
  }
  if (t < 5 * 384) {
    int l = t / 384, n = t % 384;
    b2p[t] = (n < 300) ? b2[l * 300 + n] : 0.f;
  }
}

// combined edge table: T12[l][a0*3+a1][col] = ee1[l][a0][col] + ee2[l][a1][col]
__global__ void build_t12_kernel(const float* __restrict__ ee1, const float* __restrict__ ee2,
                                 bf16_t* __restrict__ T12) {
  int id = blockIdx.x * 256 + threadIdx.x;
  if (id >= 5 * 21 * 320) return;
  int col = id % 320;
  int r = id / 320;
  int l = r / 21;
  int a = r % 21;
  int a0 = a / 3, a1 = a % 3;
  float v = 0.f;
  if (col < 300) v = ee1[((size_t)l * 7 + a0) * 300 + col] + ee2[((size_t)l * 3 + a1) * 300 + col];
  T12[id] = (bf16_t)v;
}

// ---------------- aggregation: thread-centric (node = g/40), fused BN ----------
template <bool FUSE_BN>
__global__ void aggregate_kernel(const bf16_t* __restrict__ hsrc, const int* __restrict__ rowptr,
                                 const int* __restrict__ epack, const bf16_t* __restrict__ T12L,
                                 const float* __restrict__ scale, const float* __restrict__ shift,
                                 bf16_t* __restrict__ agg, int N, int LDH) {
  const int g = blockIdx.x * 256 + threadIdx.x;
  const int w = g / 40;
  if (w >= N) return;
  const int co = (g - w * 40) * 8;

  float sc[8], sh[8];
  if (FUSE_BN) {
    f32x4 s0 = *(const f32x4*)&scale[co];
    f32x4 s1 = *(const f32x4*)&scale[co + 4];
    f32x4 t0 = *(const f32x4*)&shift[co];
    f32x4 t1 = *(const f32x4*)&shift[co + 4];
    #pragma unroll
    for (int j = 0; j < 4; j++) { sc[j] = s0[j]; sc[j + 4] = s1[j]; sh[j] = t0[j]; sh[j + 4] = t1[j]; }
  }

  const int beg = rowptr[w], end = rowptr[w + 1];
  float acc[8];
  {
    bf16x8 hv = *(const bf16x8*)&hsrc[(size_t)w * LDH + co];
    bf16x8 tv = *(const bf16x8*)&T12L[12 * 320 + co];  // self loop: a0=4,a1=0
    #pragma unroll
    for (int j = 0; j < 8; j++) {
      float v = (float)hv[j];
      if (FUSE_BN) v = fmaxf(v * sc[j] + sh[j], 0.f);
      acc[j] = v + (float)tv[j];
    }
  }
  for (int e = beg; e < end; e++) {
    const int p = epack[e];
    const int s = p & 0xFFFFF;
    const int a = (p >> 20) & 0x1F;
    bf16x8 hv = *(const bf16x8*)&hsrc[(size_t)s * LDH + co];
    bf16x8 tv = *(const bf16x8*)&T12L[a * 320 + co];
    #pragma unroll
    for (int j = 0; j < 8; j++) {
      float v = (float)hv[j];
      if (FUSE_BN) v = fmaxf(v * sc[j] + sh[j], 0.f);
      acc[j] += v + (float)tv[j];
    }
  }
  bf16x8 o;
  #pragma unroll
  for (int j = 0; j < 8; j++) o[j] = (bf16_t)acc[j];
  *(bf16x8*)&agg[(size_t)w * 320 + co] = o;
}

// ---------------- FUSED MLP: relu(A x W1 + b1) x W2 + b2, C1 never leaves LDS ----
// Block = 64-row strip, 512 threads (8 waves). A-strip [64][320] staged to LDS
// ONCE (xor-swizzled, r4's proven conflict-free scheme). Loop over 5 chunks of
// 128 C1-columns: phase1 (swapped mfma(w1f, aF) -> lane holds 4 consecutive C1
// cols -> clean 8B LDS writes into padded C1p[64][136]) then phase2 (normal
// mfma(c1f, w2f) accumulating H2 acc over all chunks). W1f/W2f are fragment-
// major: every weight fragment is ONE contiguous 1KB wave-load (fixes the r5
// 16-line gather cost by layout; W is L2-resident, ~0.9MB shared by all blocks).
// 88 MFMA per wave per barrier interval (vs 16 in the split GEMMs); C1's 256MB
// HBM round-trip per layer is eliminated.
__global__ __launch_bounds__(512) void fused_mlp_kernel(
    const bf16_t* __restrict__ agg,   // [Mp][320]
    const bf16_t* __restrict__ W1f,   // [40][10][512] frag-major
    const bf16_t* __restrict__ W2f,   // [24][20][512] frag-major
    const float* __restrict__ b1p,    // [640]
    const float* __restrict__ b2p,    // [384]
    bf16_t* __restrict__ H2,          // [Mp][384]
    float* __restrict__ sums, float* __restrict__ sumsq, int Nvalid) {
  __shared__ __align__(16) bf16_t As[10 * 64 * 32];  // 40KB: [ks][row][chunk4 swz][8]
  __shared__ __align__(16) bf16_t C1p[64 * 136];     // 17KB padded row-major

  const int tid = threadIdx.x;  // 0..511
  const int lane = tid & 63;
  const int w = tid >> 6;       // wave 0..7
  const int ml = lane & 15, quad = lane >> 4;
  const int kx = (ml >> 1) & 3;  // fragment-read swizzle key
  const size_t bm = (size_t)blockIdx.x * 64;

  // ---- stage A-strip [64][320] once: inverse-swizzled global src, linear LDS ----
  #pragma unroll
  for (int it = 0; it < 5; it++) {
    const int s = it * 512 + tid;  // 0..2559
    const int ks = s >> 8;
    const int u = s & 255;
    const int row = u >> 2;
    const int cg = (u & 3) ^ ((u >> 3) & 3);  // (u>>3)&3 == (row>>1)&3
    bf16x8 v = *(const bf16x8*)&agg[(bm + row) * 320 + ks * 32 + cg * 8];
    *(bf16x8*)&As[(size_t)s * 8] = v;
  }
  asm volatile("s_waitcnt lgkmcnt(0)" ::: "memory");
  __builtin_amdgcn_s_barrier();

  f32x4 acc1[4];
  f32x4 acc2[4][3];
  #pragma unroll
  for (int mf = 0; mf < 4; mf++)
    #pragma unroll
    for (int nf = 0; nf < 3; nf++) acc2[mf][nf] = (f32x4){0.f, 0.f, 0.f, 0.f};

  // phase1(c): acc1[mt] = C1 fragment for chunk c, wave's 16-col ntile (c*8+w).
  // Swapped operands: lane holds C1[m=mt*16+ml][n=(c*8+w)*16 + quad*4+i].
  auto phase1 = [&](int c) {
    #pragma unroll
    for (int mt = 0; mt < 4; mt++) acc1[mt] = (f32x4){0.f, 0.f, 0.f, 0.f};
    const bf16_t* wp = W1f + (((size_t)(c * 8 + w) * 10) * 64 + lane) * 8;
    #pragma unroll
    for (int ks = 0; ks < 10; ks++) {
      bf16x8 w1f = *(const bf16x8*)(wp + (size_t)ks * 512);
      #pragma unroll
      for (int mt = 0; mt < 4; mt++) {
        bf16x8 aF = *(const bf16x8*)&As[((ks * 64 + mt * 16 + ml) * 4 + (quad ^ kx)) * 8];
        acc1[mt] = __builtin_amdgcn_mfma_f32_16x16x32_bf16(w1f, aF, acc1[mt], 0, 0, 0);
      }
    }
  };

  phase1(0);

  for (int c = 0; c < 5; c++) {
    // ---- write C1 chunk: bias+relu+bf16, 4x 8B writes (4 consecutive cols/lane)
    {
      const int nloc = w * 16 + quad * 4;  // col within chunk
      f32x4 bv = *(const f32x4*)&b1p[c * 128 + nloc];
      #pragma unroll
      for (int mt = 0; mt < 4; mt++) {
        bf16x4 o;
        #pragma unroll
        for (int i = 0; i < 4; i++) {
          float v = acc1[mt][i] + bv[i];
          o[i] = (bf16_t)fmaxf(v, 0.f);
        }
        *(bf16x4*)&C1p[(mt * 16 + ml) * 136 + nloc] = o;
      }
    }
    asm volatile("s_waitcnt lgkmcnt(0)" ::: "memory");
    __builtin_amdgcn_s_barrier();

    // ---- phase2(c): acc2 += C1chunk x W2slice  (+ phase1(c+1) interleaved) ----
    #pragma unroll
    for (int ks2 = 0; ks2 < 4; ks2++) {
      bf16x8 c1f[4];
      #pragma unroll
      for (int mf = 0; mf < 4; mf++)
        c1f[mf] = *(const bf16x8*)&C1p[(mf * 16 + ml) * 136 + ks2 * 32 + quad * 8];
      #pragma unroll
      for (int nf = 0; nf < 3; nf++) {
        bf16x8 w2f = *(const bf16x8*)&W2f[(((size_t)(w * 3 + nf) * 20 + c * 4 + ks2) * 64 + lane) * 8];
        #pragma unroll
        for (int mf = 0; mf < 4; mf++)
          acc2[mf][nf] = __builtin_amdgcn_mfma_f32_16x16x32_bf16(c1f[mf], w2f, acc2[mf][nf], 0, 0, 0);
      }
    }
    if (c < 4) phase1(c + 1);  // independent: As reads + W1f loads + acc1 MFMAs
    asm volatile("s_waitcnt lgkmcnt(0)" ::: "memory");
    __builtin_amdgcn_s_barrier();  // C1p free for next chunk's writes
  }

  // ---- epilogue: H2 = acc2 + b2, fused BN column stats ----
  #pragma unroll
  for (int nf = 0; nf < 3; nf++) {
    const int colg = (w * 3 + nf) * 16 + ml;  // 0..383
    const float bv = b2p[colg];
    float s = 0.f, sq = 0.f;
    #pragma unroll
    for (int mf = 0; mf < 4; mf++) {
      #pragma unroll
      for (int i = 0; i < 4; i++) {
        const size_t rowg = bm + mf * 16 + quad * 4 + i;
        float v = acc2[mf][nf][i] + bv;
        H2[rowg * 384 + colg] = (bf16_t)v;
        const bool ok = rowg < (size_t)Nvalid;
        s += ok ? v : 0.f;
        sq += ok ? v * v : 0.f;
      }
    }
    // quads (lanes ml, ml+16, ml+32, ml+48) share colg
    s += __shfl_down(s, 16);
    sq += __shfl_down(sq, 16);
    s += __shfl_down(s, 32);
    sq += __shfl_down(sq, 32);
    if (quad == 0) {
      atomicAdd(&sums[colg], s);
      atomicAdd(&sumsq[colg], sq);
    }
  }
}

// ---------------- BN ----------------
__global__ void bn_params_kernel(const float* __restrict__ sums, const float* __restrict__ sumsq,
                                 const float* __restrict__ gamma, const float* __restrict__ beta,
                                 float* __restrict__ scale, float* __restrict__ shift, int N) {
  const int col = threadIdx.x;
  if (col >= 384) return;
  if (col >= 300) {  // pad cols: force transformed pad to 0
    scale[col] = 0.f;
    shift[col] = 0.f;
    return;
  }
  const float inv = 1.f / (float)N;
  const float mean = sums[col] * inv;
  float var = sumsq[col] * inv - mean * mean;
  if (var < 0.f) var = 0.f;
  const float sc = gamma[col] * rsqrtf(var + 1e-5f);
  scale[col] = sc;
  shift[col] = beta[col] - mean * sc;
}

// final-layer output: wave per node, lane<40 handles 8 cols, writes f32 out
__global__ void bn_apply_kernel(const bf16_t* __restrict__ H2, const float* __restrict__ scale,
                                const float* __restrict__ shift, float* __restrict__ out, int N) {
  const int w = (blockIdx.x * blockDim.x + threadIdx.x) >> 6;
  const int lane = threadIdx.x & 63;
  if (w >= N || lane >= 40) return;
  const int co = lane * 8;
  bf16x8 v8 = *(const bf16x8*)&H2[(size_t)w * 384 + co];
  f32x4 s0 = *(const f32x4*)&scale[co];
  f32x4 s1 = *(const f32x4*)&scale[co + 4];
  f32x4 t0 = *(const f32x4*)&shift[co];
  f32x4 t1 = *(const f32x4*)&shift[co + 4];
  #pragma unroll
  for (int j = 0; j < 8; j++) {
    float sc = (j < 4) ? s0[j] : s1[j - 4];
    float sh = (j < 4) ? t0[j] : t1[j - 4];
    float v = (float)v8[j] * sc + sh;
    if (co + j < 300) out[(size_t)w * 300 + co + j] = v;
  }
}

// ---------------- launch ----------------
extern "C" void kernel_launch(void* const* d_in, const int* in_sizes, int n_in,
                              void* d_out, int out_size, void* d_ws, size_t ws_size,
                              hipStream_t stream) {
  const int* x = (const int*)d_in[0];
  const int* ei = (const int*)d_in[1];
  const int* ea = (const int*)d_in[2];
  const float* xe1 = (const float*)d_in[3];
  const float* xe2 = (const float*)d_in[4];
  const float* ee1 = (const float*)d_in[5];
  const float* ee2 = (const float*)d_in[6];
  const float* w1 = (const float*)d_in[7];
  const float* b1 = (const float*)d_in[8];
  const float* w2 = (const float*)d_in[9];
  const float* b2 = (const float*)d_in[10];
  const float* gam = (const float*)d_in[11];
  const float* bet = (const float*)d_in[12];

  const int N = in_sizes[0] / 2;   // 100000
  const int E = in_sizes[1] / 2;   // 200000
  const int Mt = (N + 127) / 128;  // 782
  const size_t Mp = (size_t)Mt * 128;  // 100096 (multiple of 64)
  const int Mt2 = (int)(Mp / 64);  // 1564 fused blocks

  char* p = (char*)d_ws;
  auto take = [&](size_t b) -> char* {
    char* r = p;
    p += (b + 255) & ~(size_t)255;
    return r;
  };
  bf16_t* h    = (bf16_t*)take(Mp * 320 * 2);
  bf16_t* agg  = (bf16_t*)take(Mp * 320 * 2);
  bf16_t* H2   = (bf16_t*)take(Mp * 384 * 2);
  bf16_t* W1f  = (bf16_t*)take((size_t)5 * 40 * 10 * 512 * 2);  // 2.05 MB
  bf16_t* W2f  = (bf16_t*)take((size_t)5 * 24 * 20 * 512 * 2);  // 2.46 MB
  bf16_t* T12  = (bf16_t*)take((size_t)5 * 21 * 320 * 2);
  float* b1p   = (float*)take((size_t)5 * 640 * 4);
  float* b2p   = (float*)take((size_t)5 * 384 * 4);
  int* deg     = (int*)take((size_t)N * 4);
  int* rowptr  = (int*)take((size_t)(N + 1) * 4);
  int* cursor  = (int*)take((size_t)N * 4);
  int* part    = (int*)take(1024 * 4);
  int* epack   = (int*)take((size_t)E * 4);
  float* sums  = (float*)take(384 * 4);
  float* sumsq = (float*)take(384 * 4);
  float* scale = (float*)take(384 * 4);
  float* shift = (float*)take(384 * 4);

  // agg pad rows must be exact zeros (aggregate writes rows<N only)
  hipMemsetAsync(agg, 0, Mp * 320 * 2, stream);
  hipMemsetAsync(deg, 0, (size_t)N * 4, stream);

  const int nwb = (N + 3) / 4;  // wave-per-node kernels
  embed_kernel<<<nwb, 256, 0, stream>>>(x, xe1, xe2, h, N);

  count_deg_kernel<<<(E + 255) / 256, 256, 0, stream>>>(ei, deg, E);
  const int nsb = (N + 255) / 256;  // 391 (<=1024 for scan_block)
  scan_partial_kernel<<<nsb, 256, 0, stream>>>(deg, part, N);
  scan_block_kernel<<<1, 1024, 0, stream>>>(part, nsb);
  scan_final_kernel<<<nsb, 256, 0, stream>>>(deg, part, rowptr, cursor, N, E);
  fill_csr_kernel<<<(E + 255) / 256, 256, 0, stream>>>(ei, ea, cursor, epack, E);

  convert_w1_kernel<<<(5 * 40 * 10 * 512 + 255) / 256, 256, 0, stream>>>(w1, W1f);
  convert_w2_kernel<<<(5 * 24 * 20 * 512 + 255) / 256, 256, 0, stream>>>(w2, W2f);
  pad_bias_kernel<<<(5 * 640 + 255) / 256, 256, 0, stream>>>(b1, b2, b1p, b2p);
  build_t12_kernel<<<(5 * 21 * 320 + 255) / 256, 256, 0, stream>>>(ee1, ee2, T12);

  const int nab = (N * 40 + 255) / 256;  // thread-centric aggregate grid

  for (int l = 0; l < 5; l++) {
    if (l == 0) {
      aggregate_kernel<false><<<nab, 256, 0, stream>>>(h, rowptr, epack,
                                                       T12 + (size_t)l * 21 * 320,
                                                       scale, shift, agg, N, 320);
    } else {
      aggregate_kernel<true><<<nab, 256, 0, stream>>>(H2, rowptr, epack,
                                                      T12 + (size_t)l * 21 * 320,
                                                      scale, shift, agg, N, 384);
    }
    hipMemsetAsync(sums, 0, 384 * 4, stream);
    hipMemsetAsync(sumsq, 0, 384 * 4, stream);
    fused_mlp_kernel<<<Mt2, 512, 0, stream>>>(
        agg, W1f + (size_t)l * 40 * 10 * 512, W2f + (size_t)l * 24 * 20 * 512,
        b1p + (size_t)l * 640, b2p + (size_t)l * 384, H2, sums, sumsq, N);
    bn_params_kernel<<<1, 384, 0, stream>>>(sums, sumsq, gam + (size_t)l * 300,
                                            bet + (size_t)l * 300, scale, shift, N);
  }
  // final layer output: BN(H2) -> f32 out
  bn_apply_kernel<<<nwb, 256, 0, stream>>>(H2, scale, shift, (float*)d_out, N);
}

// Round 7
// 1300.057 us; speedup vs baseline: 1.8422x; 1.0649x over previous
//
#include <hip/hip_runtime.h>
#include <hip/hip_bf16.h>
#include <stdint.h>

typedef __bf16 bf16_t;
typedef bf16_t bf16x8 __attribute__((ext_vector_type(8)));
typedef bf16_t bf16x4 __attribute__((ext_vector_type(4)));
typedef float  f32x4  __attribute__((ext_vector_type(4)));

// ---------------- embed: h[i] = x_emb1[x[i,0]] + x_emb2[x[i,1]] ----------------
__global__ void embed_kernel(const int* __restrict__ x, const float* __restrict__ e1,
                             const float* __restrict__ e2, bf16_t* __restrict__ h, int N) {
  const int w = (blockIdx.x * blockDim.x + threadIdx.x) >> 6;
  const int lane = threadIdx.x & 63;
  if (w >= N || lane >= 40) return;
  const int t0 = x[2 * w], t1 = x[2 * w + 1];
  const int co = lane * 8;
  f32x4 a0 = *(const f32x4*)&e1[t0 * 300 + co];
  f32x4 a1 = *(const f32x4*)&e1[t0 * 300 + co + 4];
  f32x4 b0 = *(const f32x4*)&e2[t1 * 300 + co];
  f32x4 b1 = *(const f32x4*)&e2[t1 * 300 + co + 4];
  bf16x8 o;
  #pragma unroll
  for (int j = 0; j < 8; j++) {
    float v = (j < 4) ? (a0[j] + b0[j]) : (a1[j - 4] + b1[j - 4]);
    o[j] = (co + j < 300) ? (bf16_t)v : (bf16_t)0.f;
  }
  *(bf16x8*)&h[(size_t)w * 320 + co] = o;
}

// ---------------- CSR build ----------------
__global__ void count_deg_kernel(const int* __restrict__ ei, int* __restrict__ deg, int E) {
  int e = blockIdx.x * 256 + threadIdx.x;
  if (e < E) atomicAdd(&deg[ei[E + e]], 1);
}

__global__ void scan_partial_kernel(const int* __restrict__ deg, int* __restrict__ part, int N) {
  __shared__ int s[256];
  const int tid = threadIdx.x;
  const int idx = blockIdx.x * 256 + tid;
  s[tid] = (idx < N) ? deg[idx] : 0;
  __syncthreads();
  for (int off = 128; off > 0; off >>= 1) {
    if (tid < off) s[tid] += s[tid + off];
    __syncthreads();
  }
  if (tid == 0) part[blockIdx.x] = s[0];
}

__global__ void scan_block_kernel(int* __restrict__ part, int n) {  // n <= 1024
  __shared__ int s[1024];
  const int tid = threadIdx.x;
  const int v = (tid < n) ? part[tid] : 0;
  s[tid] = v;
  __syncthreads();
  for (int off = 1; off < 1024; off <<= 1) {
    int x = (tid >= off) ? s[tid - off] : 0;
    __syncthreads();
    s[tid] += x;
    __syncthreads();
  }
  if (tid < n) part[tid] = s[tid] - v;  // exclusive
}

__global__ void scan_final_kernel(const int* __restrict__ deg, const int* __restrict__ part,
                                  int* __restrict__ rowptr, int* __restrict__ cursor, int N, int E) {
  __shared__ int s[256];
  const int tid = threadIdx.x;
  const int idx = blockIdx.x * 256 + tid;
  const int v = (idx < N) ? deg[idx] : 0;
  s[tid] = v;
  __syncthreads();
  for (int off = 1; off < 256; off <<= 1) {
    int x = (tid >= off) ? s[tid - off] : 0;
    __syncthreads();
    s[tid] += x;
    __syncthreads();
  }
  if (idx < N) {
    int ex = s[tid] - v + part[blockIdx.x];
    rowptr[idx] = ex;
    cursor[idx] = ex;
  }
  if (idx == 0) rowptr[N] = E;
}

// pack src | (a0*3+a1)<<20
__global__ void fill_csr_kernel(const int* __restrict__ ei, const int* __restrict__ ea,
                                int* __restrict__ cursor, int* __restrict__ epack, int E) {
  int e = blockIdx.x * 256 + threadIdx.x;
  if (e >= E) return;
  int slot = atomicAdd(&cursor[ei[E + e]], 1);
  int a = ea[2 * e] * 3 + ea[2 * e + 1];
  epack[slot] = (ei[e] & 0xFFFFF) | (a << 20);
}

// ------------- weight convert: FRAGMENT-MAJOR layout (contiguous 1KB wave loads) --
// W1f[l][nt 40][ks 10][lane 64][8]: lane(ml,quad) elem j = W1T[nt*16+ml][ks*32+quad*8+j]
__global__ void convert_w1_kernel(const float* __restrict__ w1, bf16_t* __restrict__ o) {
  int id = blockIdx.x * 256 + threadIdx.x;
  if (id >= 5 * 40 * 10 * 512) return;
  int j = id & 7;
  int lane = (id >> 3) & 63;
  int rest = id >> 9;
  int ks = rest % 10;
  int nt = (rest / 10) % 40;
  int l = rest / 400;
  int ml = lane & 15, quad = lane >> 4;
  int n = nt * 16 + ml;
  int k = ks * 32 + quad * 8 + j;
  float v = (k < 300 && n < 600) ? w1[((size_t)l * 300 + k) * 600 + n] : 0.f;
  o[id] = (bf16_t)v;
}

// W2f[l][nt 24][ks 20][lane 64][8]: elem = W2T[nt*16+ml][ks*32+quad*8+j]
__global__ void convert_w2_kernel(const float* __restrict__ w2, bf16_t* __restrict__ o) {
  int id = blockIdx.x * 256 + threadIdx.x;
  if (id >= 5 * 24 * 20 * 512) return;
  int j = id & 7;
  int lane = (id >> 3) & 63;
  int rest = id >> 9;
  int ks = rest % 20;
  int nt = (rest / 20) % 24;
  int l = rest / 480;
  int ml = lane & 15, quad = lane >> 4;
  int n = nt * 16 + ml;
  int k = ks * 32 + quad * 8 + j;
  float v = (k < 600 && n < 300) ? w2[((size_t)l * 600 + k) * 300 + n] : 0.f;
  o[id] = (bf16_t)v;
}

// zero-padded biases: b1p[5][640], b2p[5][384]
__global__ void pad_bias_kernel(const float* __restrict__ b1, const float* __restrict__ b2,
                                float* __restrict__ b1p, float* __restrict__ b2p) {
  int t = blockIdx.x * 256 + threadIdx.x;
  if (t < 5 * 640) {
    int l = t / 640, n = t % 640;
    b1p[t] = (n < 600) ? b1[l * 600 + n] : 0.f;
  }
  if (t < 5 * 384) {
    int l = t / 384, n = t % 384;
    b2p[t] = (n < 300) ? b2[l * 300 + n] : 0.f;
  }
}

// combined edge table: T12[l][a0*3+a1][col] = ee1[l][a0][col] + ee2[l][a1][col]
__global__ void build_t12_kernel(const float* __restrict__ ee1, const float* __restrict__ ee2,
                                 bf16_t* __restrict__ T12) {
  int id = blockIdx.x * 256 + threadIdx.x;
  if (id >= 5 * 21 * 320) return;
  int col = id % 320;
  int r = id / 320;
  int l = r / 21;
  int a = r % 21;
  int a0 = a / 3, a1 = a % 3;
  float v = 0.f;
  if (col < 300) v = ee1[((size_t)l * 7 + a0) * 300 + col] + ee2[((size_t)l * 3 + a1) * 300 + col];
  T12[id] = (bf16_t)v;
}

// ---------------- aggregation: thread-centric (node = g/40), fused BN ----------
template <bool FUSE_BN>
__global__ void aggregate_kernel(const bf16_t* __restrict__ hsrc, const int* __restrict__ rowptr,
                                 const int* __restrict__ epack, const bf16_t* __restrict__ T12L,
                                 const float* __restrict__ scale, const float* __restrict__ shift,
                                 bf16_t* __restrict__ agg, int N, int LDH) {
  const int g = blockIdx.x * 256 + threadIdx.x;
  const int w = g / 40;
  if (w >= N) return;
  const int co = (g - w * 40) * 8;

  float sc[8], sh[8];
  if (FUSE_BN) {
    f32x4 s0 = *(const f32x4*)&scale[co];
    f32x4 s1 = *(const f32x4*)&scale[co + 4];
    f32x4 t0 = *(const f32x4*)&shift[co];
    f32x4 t1 = *(const f32x4*)&shift[co + 4];
    #pragma unroll
    for (int j = 0; j < 4; j++) { sc[j] = s0[j]; sc[j + 4] = s1[j]; sh[j] = t0[j]; sh[j + 4] = t1[j]; }
  }

  const int beg = rowptr[w], end = rowptr[w + 1];
  float acc[8];
  {
    bf16x8 hv = *(const bf16x8*)&hsrc[(size_t)w * LDH + co];
    bf16x8 tv = *(const bf16x8*)&T12L[12 * 320 + co];  // self loop: a0=4,a1=0
    #pragma unroll
    for (int j = 0; j < 8; j++) {
      float v = (float)hv[j];
      if (FUSE_BN) v = fmaxf(v * sc[j] + sh[j], 0.f);
      acc[j] = v + (float)tv[j];
    }
  }
  for (int e = beg; e < end; e++) {
    const int p = epack[e];
    const int s = p & 0xFFFFF;
    const int a = (p >> 20) & 0x1F;
    bf16x8 hv = *(const bf16x8*)&hsrc[(size_t)s * LDH + co];
    bf16x8 tv = *(const bf16x8*)&T12L[a * 320 + co];
    #pragma unroll
    for (int j = 0; j < 8; j++) {
      float v = (float)hv[j];
      if (FUSE_BN) v = fmaxf(v * sc[j] + sh[j], 0.f);
      acc[j] += v + (float)tv[j];
    }
  }
  bf16x8 o;
  #pragma unroll
  for (int j = 0; j < 8; j++) o[j] = (bf16_t)acc[j];
  *(bf16x8*)&agg[(size_t)w * 320 + co] = o;
}

// ---------------- FUSED MLP v2: 2x2 phase1 map, XOR-slot C1p, double-buffer -----
// Block = 64-row strip, 8 waves. As[10][64][4 slots] staged once (write/read XOR
// pair -> canonical frags, proven 0-conflict). phase1: wave (rg=w>>2, cg=w&3)
// computes 32 rows x 32 cols of the 128-col chunk: 20 aF LDS reads (2x fewer
// than v1) + 20 frag-major w1f loads + 40 MFMA. C1p: 2 x 16KB [64][16 slots of
// 16B], physical slot = logical ^ (row&7) on BOTH write and read (involution ->
// canonical data, optimal bank spread). Double-buffered: phase1(c+1)->bufB runs
// with phase2(c)<-bufA; ONE lgkmcnt(0)+s_barrier per chunk (7 barriers/block vs
// 11; w1f/w2f vmem loads stay in flight across barriers).
__global__ __launch_bounds__(512, 4) void fused_mlp_kernel(
    const bf16_t* __restrict__ agg,   // [Mp][320]
    const bf16_t* __restrict__ W1f,   // [40][10][512] frag-major
    const bf16_t* __restrict__ W2f,   // [24][20][512] frag-major
    const float* __restrict__ b1p,    // [640]
    const float* __restrict__ b2p,    // [384]
    bf16_t* __restrict__ H2,          // [Mp][384]
    float* __restrict__ sums, float* __restrict__ sumsq, int Nvalid) {
  __shared__ __align__(16) bf16_t As[10 * 64 * 32];  // 40KB
  __shared__ __align__(16) bf16_t C1pA[64 * 128];    // 16KB, XOR-slot layout
  __shared__ __align__(16) bf16_t C1pB[64 * 128];    // 16KB

  const int tid = threadIdx.x;  // 0..511
  const int lane = tid & 63;
  const int w = tid >> 6;       // wave 0..7
  const int ml = lane & 15, quad = lane >> 4;
  const int kx = (ml >> 1) & 3;   // As fragment-read swizzle key
  const int k7 = ml & 7;          // C1p slot swizzle key (== row&7 for row=16t+ml)
  const int rg = w >> 2, cg = w & 3;  // phase1 2x2 wave map
  const size_t bm = (size_t)blockIdx.x * 64;

  // ---- stage A-strip [64][320] once: inverse-swizzled global src, linear LDS ----
  #pragma unroll
  for (int it = 0; it < 5; it++) {
    const int s = it * 512 + tid;  // 0..2559
    const int ks = s >> 8;
    const int u = s & 255;
    const int row = u >> 2;
    const int cgl = (u & 3) ^ ((u >> 3) & 3);  // (u>>3)&3 == (row>>1)&3
    bf16x8 v = *(const bf16x8*)&agg[(bm + row) * 320 + ks * 32 + cgl * 8];
    *(bf16x8*)&As[(size_t)s * 8] = v;
  }
  asm volatile("s_waitcnt lgkmcnt(0)" ::: "memory");
  __builtin_amdgcn_s_barrier();
  __builtin_amdgcn_sched_barrier(0);

  f32x4 acc2[4][3];
  #pragma unroll
  for (int mf = 0; mf < 4; mf++)
    #pragma unroll
    for (int nf = 0; nf < 3; nf++) acc2[mf][nf] = (f32x4){0.f, 0.f, 0.f, 0.f};

  // phase1(c): wave computes C1[rg*32 .. +32][cg*32 .. +32 within chunk c].
  // Swapped mfma(w1f, aF): lane holds C1[m = base+ml][n = quad*4+i block].
  auto phase1 = [&](int c, bf16_t* dst) {
    f32x4 a1[2][2];
    #pragma unroll
    for (int mi = 0; mi < 2; mi++)
      #pragma unroll
      for (int ni = 0; ni < 2; ni++) a1[mi][ni] = (f32x4){0.f, 0.f, 0.f, 0.f};
    const int nt0 = c * 8 + cg * 2;
    #pragma unroll
    for (int ks = 0; ks < 10; ks++) {
      bf16x8 w1f0 = *(const bf16x8*)&W1f[(((size_t)nt0 * 10 + ks) * 64 + lane) * 8];
      bf16x8 w1f1 = *(const bf16x8*)&W1f[(((size_t)(nt0 + 1) * 10 + ks) * 64 + lane) * 8];
      #pragma unroll
      for (int mi = 0; mi < 2; mi++) {
        bf16x8 aF = *(const bf16x8*)&As[((ks * 64 + rg * 32 + mi * 16 + ml) * 4 + (quad ^ kx)) * 8];
        a1[mi][0] = __builtin_amdgcn_mfma_f32_16x16x32_bf16(w1f0, aF, a1[mi][0], 0, 0, 0);
        a1[mi][1] = __builtin_amdgcn_mfma_f32_16x16x32_bf16(w1f1, aF, a1[mi][1], 0, 0, 0);
      }
    }
    // write: bias+relu -> bf16x4 at logical cols cg*32+ni*16+quad*4, XOR-slot addr
    #pragma unroll
    for (int mi = 0; mi < 2; mi++) {
      const int row = rg * 32 + mi * 16 + ml;
      #pragma unroll
      for (int ni = 0; ni < 2; ni++) {
        const int colb = cg * 32 + ni * 16 + quad * 4;   // within chunk
        f32x4 bv = *(const f32x4*)&b1p[c * 128 + colb];
        bf16x4 o;
        #pragma unroll
        for (int i = 0; i < 4; i++) o[i] = (bf16_t)fmaxf(a1[mi][ni][i] + bv[i], 0.f);
        const int ls = colb >> 3;       // logical 16B slot
        const int off = colb & 7;       // 0 or 4
        *(bf16x4*)&dst[row * 128 + ((ls ^ k7) * 8) + off] = o;
      }
    }
  };

  // phase2(c): acc2 += C1chunk x W2slice; wave owns output ntiles w*3..w*3+2
  auto phase2 = [&](int c, const bf16_t* src) {
    #pragma unroll
    for (int ks2 = 0; ks2 < 4; ks2++) {
      bf16x8 c1f[4];
      #pragma unroll
      for (int mf = 0; mf < 4; mf++) {
        const int row = mf * 16 + ml;
        const int ls = ks2 * 4 + quad;
        c1f[mf] = *(const bf16x8*)&src[row * 128 + ((ls ^ k7) * 8)];
      }
      #pragma unroll
      for (int nf = 0; nf < 3; nf++) {
        bf16x8 w2f = *(const bf16x8*)&W2f[(((size_t)(w * 3 + nf) * 20 + c * 4 + ks2) * 64 + lane) * 8];
        #pragma unroll
        for (int mf = 0; mf < 4; mf++)
          acc2[mf][nf] = __builtin_amdgcn_mfma_f32_16x16x32_bf16(c1f[mf], w2f, acc2[mf][nf], 0, 0, 0);
      }
    }
  };

  phase1(0, C1pA);
  asm volatile("s_waitcnt lgkmcnt(0)" ::: "memory");
  __builtin_amdgcn_s_barrier();
  __builtin_amdgcn_sched_barrier(0);

  #pragma unroll
  for (int c = 0; c < 5; c++) {
    bf16_t* cur = (c & 1) ? C1pB : C1pA;
    bf16_t* oth = (c & 1) ? C1pA : C1pB;
    if (c < 4) phase1(c + 1, oth);  // writes other buffer: no hazard with phase2
    phase2(c, cur);
    asm volatile("s_waitcnt lgkmcnt(0)" ::: "memory");
    __builtin_amdgcn_s_barrier();   // writes to oth visible; reads of cur done
    __builtin_amdgcn_sched_barrier(0);
  }

  // ---- epilogue: H2 = acc2 + b2, fused BN column stats ----
  #pragma unroll
  for (int nf = 0; nf < 3; nf++) {
    const int colg = (w * 3 + nf) * 16 + ml;  // 0..383
    const float bv = b2p[colg];
    float s = 0.f, sq = 0.f;
    #pragma unroll
    for (int mf = 0; mf < 4; mf++) {
      #pragma unroll
      for (int i = 0; i < 4; i++) {
        const size_t rowg = bm + mf * 16 + quad * 4 + i;
        float v = acc2[mf][nf][i] + bv;
        H2[rowg * 384 + colg] = (bf16_t)v;
        const bool ok = rowg < (size_t)Nvalid;
        s += ok ? v : 0.f;
        sq += ok ? v * v : 0.f;
      }
    }
    // quads (lanes ml, ml+16, ml+32, ml+48) share colg
    s += __shfl_down(s, 16);
    sq += __shfl_down(sq, 16);
    s += __shfl_down(s, 32);
    sq += __shfl_down(sq, 32);
    if (quad == 0) {
      atomicAdd(&sums[colg], s);
      atomicAdd(&sumsq[colg], sq);
    }
  }
}

// ---------------- BN ----------------
__global__ void bn_params_kernel(const float* __restrict__ sums, const float* __restrict__ sumsq,
                                 const float* __restrict__ gamma, const float* __restrict__ beta,
                                 float* __restrict__ scale, float* __restrict__ shift, int N) {
  const int col = threadIdx.x;
  if (col >= 384) return;
  if (col >= 300) {  // pad cols: force transformed pad to 0
    scale[col] = 0.f;
    shift[col] = 0.f;
    return;
  }
  const float inv = 1.f / (float)N;
  const float mean = sums[col] * inv;
  float var = sumsq[col] * inv - mean * mean;
  if (var < 0.f) var = 0.f;
  const float sc = gamma[col] * rsqrtf(var + 1e-5f);
  scale[col] = sc;
  shift[col] = beta[col] - mean * sc;
}

// final-layer output: wave per node, lane<40 handles 8 cols, writes f32 out
__global__ void bn_apply_kernel(const bf16_t* __restrict__ H2, const float* __restrict__ scale,
                                const float* __restrict__ shift, float* __restrict__ out, int N) {
  const int w = (blockIdx.x * blockDim.x + threadIdx.x) >> 6;
  const int lane = threadIdx.x & 63;
  if (w >= N || lane >= 40) return;
  const int co = lane * 8;
  bf16x8 v8 = *(const bf16x8*)&H2[(size_t)w * 384 + co];
  f32x4 s0 = *(const f32x4*)&scale[co];
  f32x4 s1 = *(const f32x4*)&scale[co + 4];
  f32x4 t0 = *(const f32x4*)&shift[co];
  f32x4 t1 = *(const f32x4*)&shift[co + 4];
  #pragma unroll
  for (int j = 0; j < 8; j++) {
    float sc = (j < 4) ? s0[j] : s1[j - 4];
    float sh = (j < 4) ? t0[j] : t1[j - 4];
    float v = (float)v8[j] * sc + sh;
    if (co + j < 300) out[(size_t)w * 300 + co + j] = v;
  }
}

// ---------------- launch ----------------
extern "C" void kernel_launch(void* const* d_in, const int* in_sizes, int n_in,
                              void* d_out, int out_size, void* d_ws, size_t ws_size,
                              hipStream_t stream) {
  const int* x = (const int*)d_in[0];
  const int* ei = (const int*)d_in[1];
  const int* ea = (const int*)d_in[2];
  const float* xe1 = (const float*)d_in[3];
  const float* xe2 = (const float*)d_in[4];
  const float* ee1 = (const float*)d_in[5];
  const float* ee2 = (const float*)d_in[6];
  const float* w1 = (const float*)d_in[7];
  const float* b1 = (const float*)d_in[8];
  const float* w2 = (const float*)d_in[9];
  const float* b2 = (const float*)d_in[10];
  const float* gam = (const float*)d_in[11];
  const float* bet = (const float*)d_in[12];

  const int N = in_sizes[0] / 2;   // 100000
  const int E = in_sizes[1] / 2;   // 200000
  const int Mt = (N + 127) / 128;  // 782
  const size_t Mp = (size_t)Mt * 128;  // 100096 (multiple of 64)
  const int Mt2 = (int)(Mp / 64);  // 1564 fused blocks

  char* p = (char*)d_ws;
  auto take = [&](size_t b) -> char* {
    char* r = p;
    p += (b + 255) & ~(size_t)255;
    return r;
  };
  bf16_t* h    = (bf16_t*)take(Mp * 320 * 2);
  bf16_t* agg  = (bf16_t*)take(Mp * 320 * 2);
  bf16_t* H2   = (bf16_t*)take(Mp * 384 * 2);
  bf16_t* W1f  = (bf16_t*)take((size_t)5 * 40 * 10 * 512 * 2);  // 2.05 MB
  bf16_t* W2f  = (bf16_t*)take((size_t)5 * 24 * 20 * 512 * 2);  // 2.46 MB
  bf16_t* T12  = (bf16_t*)take((size_t)5 * 21 * 320 * 2);
  float* b1p   = (float*)take((size_t)5 * 640 * 4);
  float* b2p   = (float*)take((size_t)5 * 384 * 4);
  int* deg     = (int*)take((size_t)N * 4);
  int* rowptr  = (int*)take((size_t)(N + 1) * 4);
  int* cursor  = (int*)take((size_t)N * 4);
  int* part    = (int*)take(1024 * 4);
  int* epack   = (int*)take((size_t)E * 4);
  float* sums  = (float*)take(384 * 4);
  float* sumsq = (float*)take(384 * 4);
  float* scale = (float*)take(384 * 4);
  float* shift = (float*)take(384 * 4);

  // agg pad rows must be exact zeros (aggregate writes rows<N only)
  hipMemsetAsync(agg, 0, Mp * 320 * 2, stream);
  hipMemsetAsync(deg, 0, (size_t)N * 4, stream);

  const int nwb = (N + 3) / 4;  // wave-per-node kernels
  embed_kernel<<<nwb, 256, 0, stream>>>(x, xe1, xe2, h, N);

  count_deg_kernel<<<(E + 255) / 256, 256, 0, stream>>>(ei, deg, E);
  const int nsb = (N + 255) / 256;  // 391 (<=1024 for scan_block)
  scan_partial_kernel<<<nsb, 256, 0, stream>>>(deg, part, N);
  scan_block_kernel<<<1, 1024, 0, stream>>>(part, nsb);
  scan_final_kernel<<<nsb, 256, 0, stream>>>(deg, part, rowptr, cursor, N, E);
  fill_csr_kernel<<<(E + 255) / 256, 256, 0, stream>>>(ei, ea, cursor, epack, E);

  convert_w1_kernel<<<(5 * 40 * 10 * 512 + 255) / 256, 256, 0, stream>>>(w1, W1f);
  convert_w2_kernel<<<(5 * 24 * 20 * 512 + 255) / 256, 256, 0, stream>>>(w2, W2f);
  pad_bias_kernel<<<(5 * 640 + 255) / 256, 256, 0, stream>>>(b1, b2, b1p, b2p);
  build_t12_kernel<<<(5 * 21 * 320 + 255) / 256, 256, 0, stream>>>(ee1, ee2, T12);

  const int nab = (N * 40 + 255) / 256;  // thread-centric aggregate grid

  for (int l = 0; l < 5; l++) {
    if (l == 0) {
      aggregate_kernel<false><<<nab, 256, 0, stream>>>(h, rowptr, epack,
                                                       T12 + (size_t)l * 21 * 320,
                                                       scale, shift, agg, N, 320);
    } else {
      aggregate_kernel<true><<<nab, 256, 0, stream>>>(H2, rowptr, epack,
                                                      T12 + (size_t)l * 21 * 320,
                                                      scale, shift, agg, N, 384);
    }
    hipMemsetAsync(sums, 0, 384 * 4, stream);
    hipMemsetAsync(sumsq, 0, 384 * 4, stream);
    fused_mlp_kernel<<<Mt2, 512, 0, stream>>>(
        agg, W1f + (size_t)l * 40 * 10 * 512, W2f + (size_t)l * 24 * 20 * 512,
        b1p + (size_t)l * 640, b2p + (size_t)l * 384, H2, sums, sumsq, N);
    bn_params_kernel<<<1, 384, 0, stream>>>(sums, sumsq, gam + (size_t)l * 300,
                                            bet + (size_t)l * 300, scale, shift, N);
  }
  // final layer output: BN(H2) -> f32 out
  bn_apply_kernel<<<nwb, 256, 0, stream>>>(H2, scale, shift, (float*)d_out, N);
}